// Round 13
// baseline (53.168 us; speedup 1.0000x reference)
//
#include <hip/hip_runtime.h>
#include <hip/hip_bf16.h>
#include <stdint.h>

// Locally-connected layer: X[128,32,32,64] f32, filters[900,576,64] f32
// -> out[128,30,30,64] f32.  900 per-location GEMMs: M=128 x N=64 x K=576.
// R13: R12 structure (1800 WGs x 256 thr, M=64/WG, 32KB LDS -> 5 WG/CU)
// + 2-DEEP A/B register prefetch at CONSTANT occupancy (+32 VGPR, ~92 < 102
// = the 5-waves/SIMD budget; removes R3's occupancy confound).
// Mechanism: at WRITE_LDS(s+1) the compiler waits only the (s+1) register
// sets; B(s+2) (issued younger this iter) stays in flight across the
// write + barrier + next compute -> the filter stream never empties.
// Roofline: 196 MB mandatory fabric traffic = 31.1us at 6.3 TB/s; R2-R12
// deliver ~4.2 TB/s (65% duty cycle) = 40.5us. This attacks the duty cycle.

typedef __attribute__((ext_vector_type(4))) float  f32x4;
typedef __attribute__((ext_vector_type(8))) short  short8;

#define BOFF 8192  // byte offset of B tile inside one LDS buffer

// XOR swizzle on 16B chunks within a 128B row.
__device__ __forceinline__ uint32_t swz_addr(uint32_t row, uint32_t inrow) {
    uint32_t chunk = inrow >> 4;
    uint32_t rem   = inrow & 15u;
    return row * 128u + (((chunk ^ row ^ (row >> 3)) & 7u) << 4) + rem;
}

__device__ __forceinline__ uint16_t f2bf_u(float x) {
    __hip_bfloat16 h = __float2bfloat16(x);
    uint16_t r;
    __builtin_memcpy(&r, &h, 2);
    return r;
}
__device__ __forceinline__ short f2bf(float x) { return (short)f2bf_u(x); }
__device__ __forceinline__ uint32_t pack2bf(float lo, float hi) {
    return (uint32_t)f2bf_u(lo) | ((uint32_t)f2bf_u(hi) << 16);
}

// Barrier that waits only LDS ops; in-flight global loads cross it.
#define BARRIER_KEEP_VMEM()                                   \
    do {                                                      \
        asm volatile("s_waitcnt lgkmcnt(0)" ::: "memory");    \
        __builtin_amdgcn_s_barrier();                         \
    } while (0)

__global__ __launch_bounds__(256)
void lc_mfma_kernel(const float* __restrict__ X,
                    const float* __restrict__ Fl,
                    float* __restrict__ Out) {
    __shared__ __align__(16) unsigned char lds[2][16384];
    // each buffer: [0,8192)    A tile 64 rows (batch) x 64 bf16, swizzled
    //              [8192,16384) B tile 64 rows (fout) x 64 bf16, swizzled

    // XCD-chunked swizzle: nwg=1800 = 8*225; a location's two WGs are
    // adjacent members on the same XCD (filter slab L2 reuse).
    const int orig = blockIdx.x;
    const int m    = (orig & 7) * 225 + (orig >> 3);
    const int l    = m >> 1;
    const int half = m & 1;

    const int oi = l / 30;
    const int oj = l % 30;
    const int tid  = threadIdx.x;
    const int lane = tid & 63;
    const int wave = tid >> 6;          // 0..3

    f32x4 acc[4];
#pragma unroll
    for (int n = 0; n < 4; ++n)
        acc[n] = f32x4{0.f, 0.f, 0.f, 0.f};

    // A staging: thread covers LDS row ar (0..63), fin quarter aq*16..+15
    const int ar = tid >> 2;
    const int aq = tid & 3;
    // B staging: thread covers f = fq*4..+3, k rows 4kq..4kq+3
    const int fq = tid & 15;
    const int kq = tid >> 4;            // 0..15

    const float* Fb = Fl + (size_t)l * (576 * 64);
    const int rowbase = half * 64;      // this WG's batch-row offset

    // 2-deep prefetch register sets: data for step t lives in set[t&1]
    float4 avA[4], avB[4];
    float4 bvA[4], bvB[4];

#define ISSUE_A(S, AV)                                                          \
    do {                                                                        \
        const int di_ = (S) / 3, dj_ = (S) % 3;                                 \
        const int h_ = oi + di_, w_ = oj + dj_;                                 \
        const float* a_ = X + (((size_t)(rowbase + ar) * 32 + h_) * 32 + w_) * 64 + aq*16; \
        AV[0] = ((const float4*)a_)[0]; AV[1] = ((const float4*)a_)[1];         \
        AV[2] = ((const float4*)a_)[2]; AV[3] = ((const float4*)a_)[3];         \
    } while (0)

#define ISSUE_B(S, BV)                                                          \
    do {                                                                        \
        const float* b_ = Fb + (size_t)((S) * 64 + 4 * kq) * 64 + fq * 4;       \
        BV[0] = *(const float4*)(b_);        BV[1] = *(const float4*)(b_ + 64); \
        BV[2] = *(const float4*)(b_ + 128);  BV[3] = *(const float4*)(b_ + 192);\
    } while (0)

#define WRITE_LDS(BUF, AV, BV)                                                  \
    do {                                                                        \
        unsigned char* L_ = lds[BUF];                                           \
        short8 p0, p1;                                                          \
        p0[0]=f2bf(AV[0].x); p0[1]=f2bf(AV[0].y); p0[2]=f2bf(AV[0].z); p0[3]=f2bf(AV[0].w); \
        p0[4]=f2bf(AV[1].x); p0[5]=f2bf(AV[1].y); p0[6]=f2bf(AV[1].z); p0[7]=f2bf(AV[1].w); \
        p1[0]=f2bf(AV[2].x); p1[1]=f2bf(AV[2].y); p1[2]=f2bf(AV[2].z); p1[3]=f2bf(AV[2].w); \
        p1[4]=f2bf(AV[3].x); p1[5]=f2bf(AV[3].y); p1[6]=f2bf(AV[3].z); p1[7]=f2bf(AV[3].w); \
        *(short8*)&L_[swz_addr(ar, aq*32 + 0 )] = p0;                           \
        *(short8*)&L_[swz_addr(ar, aq*32 + 16)] = p1;                           \
        _Pragma("unroll")                                                       \
        for (int j_ = 0; j_ < 4; ++j_) {                                        \
            const float k0_ = (&BV[0].x)[j_], k1_ = (&BV[1].x)[j_];             \
            const float k2_ = (&BV[2].x)[j_], k3_ = (&BV[3].x)[j_];             \
            *(uint32_t*)&L_[BOFF + swz_addr(fq*4 + j_, kq*8 + 0)] = pack2bf(k0_, k1_); \
            *(uint32_t*)&L_[BOFF + swz_addr(fq*4 + j_, kq*8 + 4)] = pack2bf(k2_, k3_); \
        }                                                                       \
    } while (0)

    // prologue: B(0),A(0) issued; B(1) issued YOUNGER so it stays in flight
    // across WRITE(0)'s register waits.
    ISSUE_B(0, bvA);
    ISSUE_A(0, avA);
    ISSUE_B(1, bvB);
    WRITE_LDS(0, avA, bvA);

    const int mb   = wave * 16;
    const int rsel = lane & 15;
    const int ksel = (lane >> 4) * 16;

#pragma unroll 1
    for (int s = 0; s < 9; ++s) {
        // Issue A(s+1) into set (s+1)&1, then B(s+2) into set s&1 (younger).
        // At WRITE_LDS(s+1) below the compiler waits A(s+1)/B(s+1) only;
        // B(s+2) stays in flight across write+barrier+next compute.
        if (s < 8) {
            if (((s + 1) & 1) == 0) ISSUE_A(s + 1, avA);
            else                    ISSUE_A(s + 1, avB);
        }
        if (s < 7) {
            if ((s & 1) == 0) ISSUE_B(s + 2, bvA);
            else              ISSUE_B(s + 2, bvB);
        }

        BARRIER_KEEP_VMEM();  // lds[s&1] writes (prev iter / prologue) visible

        const unsigned char* L = lds[s & 1];
#pragma unroll
        for (int kk = 0; kk < 2; ++kk) {
            const uint32_t inrow = (uint32_t)(kk * 64 + ksel);
            const short8 a0 = *(const short8*)&L[swz_addr(mb + rsel, inrow)];
            const short8 b0 = *(const short8*)&L[BOFF + swz_addr(     rsel, inrow)];
            const short8 b1 = *(const short8*)&L[BOFF + swz_addr(16 + rsel, inrow)];
            const short8 b2 = *(const short8*)&L[BOFF + swz_addr(32 + rsel, inrow)];
            const short8 b3 = *(const short8*)&L[BOFF + swz_addr(48 + rsel, inrow)];
            acc[0] = __builtin_amdgcn_mfma_f32_16x16x32_bf16(a0, b0, acc[0], 0, 0, 0);
            acc[1] = __builtin_amdgcn_mfma_f32_16x16x32_bf16(a0, b1, acc[1], 0, 0, 0);
            acc[2] = __builtin_amdgcn_mfma_f32_16x16x32_bf16(a0, b2, acc[2], 0, 0, 0);
            acc[3] = __builtin_amdgcn_mfma_f32_16x16x32_bf16(a0, b3, acc[3], 0, 0, 0);
        }

        // write step s+1 (sets (s+1)&1) into the other buffer; its previous
        // readers all passed the barrier above.
        if (s < 8) {
            if (((s + 1) & 1) == 0) WRITE_LDS(0, avA, bvA);
            else                    WRITE_LDS(1, avB, bvB);
        }
    }

    // epilogue: D layout col=lane&15, row=(lane>>4)*4+reg (m89-verified)
    const int col = lane & 15;
    const int rb  = (lane >> 4) * 4;
#pragma unroll
    for (int n = 0; n < 4; ++n)
#pragma unroll
        for (int i = 0; i < 4; ++i) {
            const int row = rowbase + mb + rb + i;   // batch index
            const int f   = n * 16 + col;            // fout index
            Out[((size_t)row * 900 + l) * 64 + f] = acc[n][i];
        }
}

extern "C" void kernel_launch(void* const* d_in, const int* in_sizes, int n_in,
                              void* d_out, int out_size, void* d_ws, size_t ws_size,
                              hipStream_t stream) {
    const float* X  = (const float*)d_in[0];   // [128,32,32,64]
    const float* Fl = (const float*)d_in[1];   // [900,576,64]
    float* Out = (float*)d_out;                // [128,30,30,64]
    lc_mfma_kernel<<<dim3(1800), dim3(256), 0, stream>>>(X, Fl, Out);
}